// Round 10
// baseline (5180.660 us; speedup 1.0000x reference)
//
#include <hip/hip_runtime.h>

// LSTM: B=128, S=256, I=512, H=1024, O=512.
// R18 = R17 (flag protocol, per-wave poll, XCD-pair placement, coalesced
// prep) with the LAST untested structural lever: CLIQUE SIZE HALVED.
//  128 blocks x 512 threads (8 waves: ct=0..3 col-tiles, kh=0..1 K-halves).
//  Each block = 32 rows x 128 gate-cols; clique per rq = 32 producers
//  (was 64). Per-wave work, MFMA shapes, WcF/xA/hA layouts and consumer
//  addressing are UNCHANGED; only the decode, publish (2KB as two coalesced
//  1KB wave0 bursts), hstage(2KB)/scr(16KB), and flag target (32*t) change.
//  Rationale: step time has been invariant (+-3%) across 13 protocol/
//  placement variants -> hypothesis: wait = max over N producers' flag
//  arrival (skew / max-of-N jitter), so the lever is N: 64 -> 32. Also
//  halves fabric + poll contention. Occupancy: 2 waves/SIMD @ <=232 VGPR.
// h: published via coalesced sc0/sc1 write-through stores (wave0-solo, ack
// via vmcnt(0), single atomicAdd per block), consumed CACHED from rotating
// per-step buffers. One-time acquire fence at start; no per-step fences.

#define B_ 128
#define S_ 256
#define I_ 512
#define H_ 1024
#define O_ 512

typedef unsigned short u16;
typedef unsigned int u32;
typedef unsigned long long u64;

typedef short v8s __attribute__((ext_vector_type(8)));
typedef unsigned int v4u __attribute__((ext_vector_type(4)));
typedef float v16f __attribute__((ext_vector_type(16)));
typedef float v4f __attribute__((ext_vector_type(4)));

__device__ __forceinline__ u16 f2bf(float f) {
  u32 u = __float_as_uint(f);
  u32 r = (u + 0x7fffu + ((u >> 16) & 1u)) >> 16;   // RNE
  return (u16)r;
}
__device__ __forceinline__ u32 pack2(float a, float b) {
  return (u32)f2bf(a) | ((u32)f2bf(b) << 16);
}
__device__ __forceinline__ uint4 cvt8(const float* __restrict__ s) {
  float4 f0 = ((const float4*)s)[0];
  float4 f1 = ((const float4*)s)[1];
  uint4 o;
  o.x = pack2(f0.x, f0.y); o.y = pack2(f0.z, f0.w);
  o.z = pack2(f1.x, f1.y); o.w = pack2(f1.z, f1.w);
  return o;
}

__device__ __forceinline__ uint4 uc_ld16(const u16* p) {
  u64 lo = __hip_atomic_load((const u64*)p, __ATOMIC_RELAXED, __HIP_MEMORY_SCOPE_AGENT);
  u64 hi = __hip_atomic_load((const u64*)p + 1, __ATOMIC_RELAXED, __HIP_MEMORY_SCOPE_AGENT);
  uint4 v; v.x = (u32)lo; v.y = (u32)(lo >> 32); v.z = (u32)hi; v.w = (u32)(hi >> 32);
  return v;
}
// Agent-visible 16B publish store: plain dwordx4, write-through (sc0 sc1).
// Coalesces across lanes; updates local L2 + LLC. Ack via caller's vmcnt(0).
__device__ __forceinline__ void uc_st16(u16* p, uint4 v) {
  v4u d;
  d.x = v.x; d.y = v.y; d.z = v.z; d.w = v.w;
  asm volatile("global_store_dwordx4 %0, %1, off sc0 sc1"
               :: "v"(p), "v"(d) : "memory");
}

// ---------------------------------------------------------------- prep ----
__global__ void lstm_prep(
    const float* __restrict__ x,
    const float* __restrict__ Whf, const float* __restrict__ Whi,
    const float* __restrict__ Whg, const float* __restrict__ Who,
    const float* __restrict__ Wxf, const float* __restrict__ Wxi,
    const float* __restrict__ Wxg, const float* __restrict__ Wxo,
    const float* __restrict__ bfp, const float* __restrict__ bip,
    const float* __restrict__ bgp, const float* __restrict__ bop,
    const float* __restrict__ Why,
    u16* __restrict__ xt, u16* __restrict__ Wc, float* __restrict__ bc,
    u16* __restrict__ WhyT, u16* __restrict__ hbuf, u32* __restrict__ barrier)
{
  const int gid = blockIdx.x * blockDim.x + threadIdx.x;
  const int gsz = gridDim.x * blockDim.x;

  if (gid < 256) barrier[gid] = 0u;

  // xA fill, DST-major (coalesced writes): unit v = ((t*4+rqb)*64+w8)*32+row
  // <- x[(rqb*32+row)*(S*I) + t*I + w8*8 .. +8]. Reads are 32B gathers.
  for (int v = gid; v < (S_ * B_ * I_ / 8); v += gsz) {
    int row = v & 31;
    int w8  = (v >> 5) & 63;
    int rqb = (v >> 11) & 3;
    int t   = v >> 13;
    int b   = rqb * 32 + row;
    size_t src = (size_t)b * (S_ * I_) + t * I_ + w8 * 8;
    ((uint4*)xt)[v] = cvt8(x + src);
  }

  // WcF[w8 0..191][colG 0..4095]: w8<64 -> Wx k=w8*8 ; w8>=64 -> Wh k=(w8-64)*8
  for (int o = gid; o < 192 * 4096; o += gsz) {
    int w8 = o >> 12;
    int colG = o & 4095;
    int unit = ((colG >> 6) << 4) + (((colG >> 5) & 1) << 3) + ((colG >> 2) & 7);
    int g = colG & 3;
    const float* Whp = (g == 0) ? Whf : (g == 1) ? Whi : (g == 2) ? Whg : Who;
    const float* Wxp = (g == 0) ? Wxf : (g == 1) ? Wxi : (g == 2) ? Wxg : Wxo;
    const float* s = (w8 < 64) ? (Wxp + (size_t)unit * 512 + w8 * 8)
                               : (Whp + (size_t)unit * 1024 + (w8 - 64) * 8);
    ((uint4*)Wc)[o] = cvt8(s);
  }

  // bias (colG-indexed)
  for (int n = gid; n < 4096; n += gsz) {
    int unit = ((n >> 6) << 4) + (((n >> 5) & 1) << 3) + ((n >> 2) & 7);
    int g = n & 3;
    const float* bp = (g == 0) ? bfp : (g == 1) ? bip : (g == 2) ? bgp : bop;
    bc[n] = bp[unit];
  }

  // Why -> bf16 (row-major [o][k])
  for (int v = gid; v < (O_ * H_ / 8); v += gsz) {
    int flat = v * 8;
    *(uint4*)(WhyT + flat) = cvt8(Why + flat);
  }

  // zero hA[0] and hA[1]
  for (int v = gid; v < 2 * 16384; v += gsz) {
    uint4 z; z.x = 0; z.y = 0; z.z = 0; z.w = 0;
    ((uint4*)hbuf)[v] = z;
  }
}

// ------------------------------------------------------ persistent LSTM ----
__global__ __launch_bounds__(512, 1) void lstm_seq(
    const u16* __restrict__ xt, const u16* __restrict__ Wc,
    const float* __restrict__ bc, u16* __restrict__ hbuf,
    const u16* __restrict__ WhyT, const float* __restrict__ WhyB,
    float* __restrict__ out, u32* __restrict__ barrier, int rotFlag)
{
  __shared__ float scr[4096];   // cross-kh partial-sum exchange (16 KB)
  __shared__ u16 hstage[1024];  // h gather tile: [row 0..31][unitL 0..31]

  const int tid  = threadIdx.x;
  const int lane = tid & 63;
  const int w    = tid >> 6;          // 0..7
  const int ct   = w & 3;             // col tile (32 cols), 0..3
  const int kh   = w >> 2;            // K half
  // XCD-local clique decode: blockIdx%8 ~ XCD (MI355X heuristic). Clique rq
  // = 32 blocks on XCD pair {2rq,2rq+1}; cg2 parity = XCD within pair.
  const int rq   = (blockIdx.x & 7) >> 1;                        // rows rq*32..+31
  const int cg2  = ((blockIdx.x >> 3) << 1) | (blockIdx.x & 1);  // 0..31, cols cg2*128..+127
  const bool rot = (rotFlag != 0);

  const int colN  = lane & 31;
  const int kgsel = lane >> 5;
  const int colG  = cg2 * 128 + ct * 32 + colN;
  const int gate  = colN & 3;                  // 0=f 1=i 2=g 3=o
  const int unitL = ct * 8 + (colN >> 2);      // 0..31 (local hidden unit)
  const float bias = bc[colG];

  const uint4* xA4  = (const uint4*)xt;
  const uint4* WcF4 = (const uint4*)Wc;
  uint4*       HA4  = (uint4*)hbuf;

  const int xaOff = rq * 2048 + kh * 1024 + lane;                 // + t*8192 + kb*64
  const int xbOff = kh * 131072 + kgsel * 4096 + colG;            // + kb*8192
  const int haOff = rq * 4096 + kh * 2048 + lane;                 // + tb + kb*64
  const int hbOff = 262144 + kh * 262144 + kgsel * 4096 + colG;   // + kb*8192

  float c[8];
#pragma unroll
  for (int i = 0; i < 8; ++i) c[i] = 0.f;

  // One-time acquire: drop stale memset-poison / pre-prep lines so cached
  // reads of rotating h buffers (and the B preload) are correct.
  __builtin_amdgcn_fence(__ATOMIC_ACQUIRE, "agent");
  __syncthreads();

  // ---- park ALL weight B-frags in registers (192 regs/lane, AV->AGPR) ----
  v8s Bx[16], Bh[32];
  {
    const uint4* bx = WcF4 + xbOff;
#pragma unroll
    for (int kb = 0; kb < 16; ++kb)
      Bx[kb] = __builtin_bit_cast(v8s, bx[(size_t)kb * 8192]);
    const uint4* bh = WcF4 + hbOff;
#pragma unroll
    for (int kb = 0; kb < 32; ++kb)
      Bh[kb] = __builtin_bit_cast(v8s, bh[(size_t)kb * 8192]);
  }

  v16f acc0, acc1;

#pragma unroll 1
  for (int t = 0; t < S_; ++t) {
    const size_t tb = rot ? (size_t)t * 16384 : (size_t)(t & 1) * 16384;
    const size_t tn = rot ? (size_t)(t + 1) * 16384 : (size_t)((t & 1) ^ 1) * 16384;

#pragma unroll
    for (int i = 0; i < 16; ++i) { acc0[i] = 0.f; acc1[i] = 0.f; }

    // ---- x-phase: burst-load 16 A-frags, then MFMA against parked Bx ----
    {
      const uint4* ax = xA4 + (size_t)t * 8192 + xaOff;
      v8s xr[16];
#pragma unroll
      for (int kb = 0; kb < 16; ++kb)
        xr[kb] = __builtin_bit_cast(v8s, ax[kb * 64]);
#pragma unroll
      for (int kb = 0; kb < 16; ++kb) {
        if (kb & 1) acc1 = __builtin_amdgcn_mfma_f32_32x32x16_bf16(xr[kb], Bx[kb], acc1, 0, 0, 0);
        else        acc0 = __builtin_amdgcn_mfma_f32_32x32x16_bf16(xr[kb], Bx[kb], acc0, 0, 0, 0);
      }
    }

    // ---- rq-group wait: PER-WAVE lane0 poll, no barrier (32 producers) ----
    if (t > 0) {
      if (lane == 0) {
        u32 spins = 0;
        while (__hip_atomic_load(&barrier[rq * 64], __ATOMIC_RELAXED,
                                 __HIP_MEMORY_SCOPE_AGENT) < 32u * (u32)t) {
          if (++spins > (1u << 22)) break;   // safety valve
        }
      }
      // implicit reconvergence gates the wave
    }

    // ---- h-phase: burst-load 32 A-frags, MFMA against parked Bh ----
    {
      const uint4* ah = HA4 + tb + haOff;
      v8s hr[32];
      if (rot) {
#pragma unroll
        for (int kb = 0; kb < 32; ++kb)
          hr[kb] = __builtin_bit_cast(v8s, ah[kb * 64]);
      } else {
#pragma unroll
        for (int kb = 0; kb < 32; ++kb)
          hr[kb] = __builtin_bit_cast(v8s, uc_ld16((const u16*)(ah + kb * 64)));
      }
#pragma unroll
      for (int kb = 0; kb < 32; ++kb) {
        if (kb & 1) acc1 = __builtin_amdgcn_mfma_f32_32x32x16_bf16(hr[kb], Bh[kb], acc1, 0, 0, 0);
        else        acc0 = __builtin_amdgcn_mfma_f32_32x32x16_bf16(hr[kb], Bh[kb], acc0, 0, 0, 0);
      }
    }

    // ---- cross-kh reduce, gates, state update ----
    float aT[16];
#pragma unroll
    for (int i = 0; i < 16; ++i) aT[i] = acc0[i] + acc1[i];
    {
      int h2 = 1 - kh;
#pragma unroll
      for (int i = 0; i < 8; ++i)
        scr[ct * 1024 + h2 * 512 + i * 64 + lane] = aT[h2 * 8 + i];
    }
    __syncthreads();

    const bool lastT = (t == S_ - 1);
#pragma unroll
    for (int i = 0; i < 8; ++i) {
      int r = kh * 8 + i;
      float pre = aT[r] + scr[ct * 1024 + kh * 512 + i * 64 + lane] + bias;
      // gate 2 -> tanh (overflow-safe), others -> sigmoid
      float e = __expf((gate == 2) ? (2.f * pre) : (-pre));
      float act = (gate == 2) ? (1.f - 2.f / (e + 1.f)) : (1.f / (1.f + e));
      int qb = lane & ~3;   // quad holds f,i,g,o of one (row,unit)
      float F = __shfl(act, qb + 0, 64);
      float I = __shfl(act, qb + 1, 64);
      float G = __shfl(act, qb + 2, 64);
      float O = __shfl(act, qb + 3, 64);
      float cn = fmaf(F, c[i], I * G);
      c[i] = cn;
      float e2 = __expf(2.f * cn);
      float hv = O * (1.f - 2.f / (e2 + 1.f));
      if (gate == 0) {
        int rowL = (r & 3) + ((r >> 2) << 3) + (kgsel << 2);   // 0..31
        hstage[rowL * 32 + unitL] = f2bf(hv);
        if (lastT) {
          int grow = rq * 32 + rowL;
          int gunit = cg2 * 32 + unitL;
          out[65536 + grow * H_ + gunit] = hv;    // h output (fp32)
          out[196608 + grow * H_ + gunit] = cn;   // c output (fp32)
        }
      }
    }
    __syncthreads();

    // ---- publish: wave0 only (other 7 waves run ahead to x of t+1; the
    // per-wave wait of t+1 cannot pass until our flag-add lands, which is
    // after wave0's hstage read -- hstage/scr reuse stays ordered). Block
    // owns HA4 units {4cg2..4cg2+3} x 32 rows = 2KB, two coalesced 1KB
    // bursts. Single atomicAdd advances the per-rq counter (target 32/step).
    if (tid < 64) {
      int row = lane & 31;
      int ch0 = lane >> 5;                       // chunks 0..1, then 2..3
      uint4 v0 = ((const uint4*)hstage)[row * 4 + ch0];
      uc_st16((u16*)(HA4 + tn + rq * 4096 + (size_t)(4 * cg2 + ch0) * 32 + row), v0);
      uint4 v1 = ((const uint4*)hstage)[row * 4 + ch0 + 2];
      uc_st16((u16*)(HA4 + tn + rq * 4096 + (size_t)(4 * cg2 + ch0 + 2) * 32 + row), v1);
      asm volatile("s_waitcnt vmcnt(0)" ::: "memory");
      if (tid == 0)
        atomicAdd(&barrier[rq * 64], 1u);
    }
  }

  // ---- full barrier (4 aggregated counters), then out = h @ Why^T + b ----
  {
    if (tid < 4) {
      u32 spins = 0;
      while (__hip_atomic_load(&barrier[tid * 64], __ATOMIC_RELAXED,
                               __HIP_MEMORY_SCOPE_AGENT) < 32u * (u32)S_) {
        __builtin_amdgcn_s_sleep(2);
        if (++spins > (1u << 22)) break;
      }
    }
  }
  __syncthreads();

  if (blockIdx.x < 32 && w < 4) {
    const int wg = blockIdx.x;
    const uint4* HF = HA4 + (rot ? (size_t)S_ * 16384 : 0);
    const int l15 = lane & 15;
    const int l4 = lane >> 4;
    const int colO = (wg << 4) + l15;
    v4f o0, o1;
#pragma unroll
    for (int i = 0; i < 4; ++i) { o0[i] = 0.f; o1[i] = 0.f; }
#pragma unroll 4
    for (int kc = 0; kc < 32; ++kc) {
      v8s bfrag = *(const v8s*)(WhyT + (size_t)colO * H_ + kc * 32 + (l4 << 3));
      size_t i0 = (size_t)w * 4096 + kc * 128 + l4 * 32 + l15;
      v8s a0, a1;
      if (rot) {
        a0 = __builtin_bit_cast(v8s, HF[i0]);
        a1 = __builtin_bit_cast(v8s, HF[i0 + 16]);
      } else {
        a0 = __builtin_bit_cast(v8s, uc_ld16((const u16*)(HF + i0)));
        a1 = __builtin_bit_cast(v8s, uc_ld16((const u16*)(HF + i0 + 16)));
      }
      o0 = __builtin_amdgcn_mfma_f32_16x16x32_bf16(a0, bfrag, o0, 0, 0, 0);
      o1 = __builtin_amdgcn_mfma_f32_16x16x32_bf16(a1, bfrag, o1, 0, 0, 0);
    }
    float bO = WhyB[colO];
#pragma unroll
    for (int r2 = 0; r2 < 4; ++r2) {
      int row = (w << 5) + (l4 << 2) + r2;
      out[row * O_ + colO] = o0[r2] + bO;
      out[(row + 16) * O_ + colO] = o1[r2] + bO;
    }
  }
}

// ------------------------------------------------------------- launch ----
extern "C" void kernel_launch(void* const* d_in, const int* in_sizes, int n_in,
                              void* d_out, int out_size, void* d_ws, size_t ws_size,
                              hipStream_t stream) {
  const float* x    = (const float*)d_in[0];
  const float* Wxf  = (const float*)d_in[1];
  const float* bf_  = (const float*)d_in[2];
  const float* Whf  = (const float*)d_in[3];
  const float* Wxi  = (const float*)d_in[4];
  const float* bi_  = (const float*)d_in[5];
  const float* Whi  = (const float*)d_in[6];
  const float* Wxg  = (const float*)d_in[7];
  const float* bg_  = (const float*)d_in[8];
  const float* Whg  = (const float*)d_in[9];
  const float* Wxo  = (const float*)d_in[10];
  const float* bo_  = (const float*)d_in[11];
  const float* Who  = (const float*)d_in[12];
  const float* Why  = (const float*)d_in[13];
  const float* Whyb = (const float*)d_in[14];

  char* ws = (char*)d_ws;
  u16*   xtp  = (u16*)(ws);                    // xA: 33,554,432 B
  u16*   Wcp  = (u16*)(ws + 33554432);         // WcF: 12,582,912 B
  float* bcp  = (float*)(ws + 46137344);       //     16,384 B
  u16*   WhyT = (u16*)(ws + 46153728);         //  1,048,576 B
  u32*   barp = (u32*)(ws + 47202304);         //      1,024 B (4 padded counters)
  u16*   hbuf = (u16*)(ws + 47203328);         // hA: rot 257*256KB else 512KB
  float* outp = (float*)d_out;

  const size_t need_rot = 47203328ull + 257ull * 262144ull;  // ~114.6 MB
  int rot = (ws_size >= need_rot) ? 1 : 0;

  lstm_prep<<<dim3(1024), dim3(256), 0, stream>>>(
      x, Whf, Whi, Whg, Who, Wxf, Wxi, Wxg, Wxo,
      bf_, bi_, bg_, bo_, Why, xtp, Wcp, bcp, WhyT, hbuf, barp);

  lstm_seq<<<dim3(128), dim3(512), 0, stream>>>(
      xtp, Wcp, bcp, hbuf, WhyT, Whyb, outp, barp, rot);
}

// Round 11
// 2013.746 us; speedup vs baseline: 2.5726x; 2.5726x over previous
//
#include <hip/hip_runtime.h>

// LSTM: B=128, S=256, I=512, H=1024, O=512.
// R19 = R17 EXACTLY (flag protocol, per-wave lane0 poll, XCD-pair clique
// placement, coalesced prep, 256 blocks x 256 thr, 228 VGPR, parked
// weights) + ONE change:
//  PER-K-HALF COUNTERS: consumer wave kh only reads h-units published by
//  producers cg in [kh*32,(kh+1)*32) -- 32 blocks, not 64. The single
//  per-rq counter made every wave wait on all 64 (max-of-64 skew). Split:
//  producer adds to counter[rq][cg>>5] (two u32s 128B apart); consumer
//  wave kh polls counter[rq][kh] >= 32*t. Halves each wait's dependency
//  population AND decouples the two halves' straggler tails.
//  (R18's 512-thread N-halving attempt was confounded: compiler allocated
//  128 VGPR -> the 192 parked weight regs spilled to scratch, FETCH 3.8GB.
//  This variant tests N with zero occupancy/register risk.)
// h: published via coalesced sc0/sc1 write-through stores (wave0-solo, ack
// via vmcnt(0), single atomicAdd per block), consumed CACHED from rotating
// per-step buffers. One-time acquire fence at start; no per-step fences.

#define B_ 128
#define S_ 256
#define I_ 512
#define H_ 1024
#define O_ 512

typedef unsigned short u16;
typedef unsigned int u32;
typedef unsigned long long u64;

typedef short v8s __attribute__((ext_vector_type(8)));
typedef unsigned int v4u __attribute__((ext_vector_type(4)));
typedef float v16f __attribute__((ext_vector_type(16)));
typedef float v4f __attribute__((ext_vector_type(4)));

__device__ __forceinline__ u16 f2bf(float f) {
  u32 u = __float_as_uint(f);
  u32 r = (u + 0x7fffu + ((u >> 16) & 1u)) >> 16;   // RNE
  return (u16)r;
}
__device__ __forceinline__ u32 pack2(float a, float b) {
  return (u32)f2bf(a) | ((u32)f2bf(b) << 16);
}
__device__ __forceinline__ uint4 cvt8(const float* __restrict__ s) {
  float4 f0 = ((const float4*)s)[0];
  float4 f1 = ((const float4*)s)[1];
  uint4 o;
  o.x = pack2(f0.x, f0.y); o.y = pack2(f0.z, f0.w);
  o.z = pack2(f1.x, f1.y); o.w = pack2(f1.z, f1.w);
  return o;
}

__device__ __forceinline__ uint4 uc_ld16(const u16* p) {
  u64 lo = __hip_atomic_load((const u64*)p, __ATOMIC_RELAXED, __HIP_MEMORY_SCOPE_AGENT);
  u64 hi = __hip_atomic_load((const u64*)p + 1, __ATOMIC_RELAXED, __HIP_MEMORY_SCOPE_AGENT);
  uint4 v; v.x = (u32)lo; v.y = (u32)(lo >> 32); v.z = (u32)hi; v.w = (u32)(hi >> 32);
  return v;
}
// Agent-visible 16B publish store: plain dwordx4, write-through (sc0 sc1).
// Coalesces across lanes; updates local L2 + LLC. Ack via caller's vmcnt(0).
__device__ __forceinline__ void uc_st16(u16* p, uint4 v) {
  v4u d;
  d.x = v.x; d.y = v.y; d.z = v.z; d.w = v.w;
  asm volatile("global_store_dwordx4 %0, %1, off sc0 sc1"
               :: "v"(p), "v"(d) : "memory");
}

// ---------------------------------------------------------------- prep ----
__global__ void lstm_prep(
    const float* __restrict__ x,
    const float* __restrict__ Whf, const float* __restrict__ Whi,
    const float* __restrict__ Whg, const float* __restrict__ Who,
    const float* __restrict__ Wxf, const float* __restrict__ Wxi,
    const float* __restrict__ Wxg, const float* __restrict__ Wxo,
    const float* __restrict__ bfp, const float* __restrict__ bip,
    const float* __restrict__ bgp, const float* __restrict__ bop,
    const float* __restrict__ Why,
    u16* __restrict__ xt, u16* __restrict__ Wc, float* __restrict__ bc,
    u16* __restrict__ WhyT, u16* __restrict__ hbuf, u32* __restrict__ barrier)
{
  const int gid = blockIdx.x * blockDim.x + threadIdx.x;
  const int gsz = gridDim.x * blockDim.x;

  if (gid < 256) barrier[gid] = 0u;

  // xA fill, DST-major (coalesced writes): unit v = ((t*4+rqb)*64+w8)*32+row
  // <- x[(rqb*32+row)*(S*I) + t*I + w8*8 .. +8]. Reads are 32B gathers.
  for (int v = gid; v < (S_ * B_ * I_ / 8); v += gsz) {
    int row = v & 31;
    int w8  = (v >> 5) & 63;
    int rqb = (v >> 11) & 3;
    int t   = v >> 13;
    int b   = rqb * 32 + row;
    size_t src = (size_t)b * (S_ * I_) + t * I_ + w8 * 8;
    ((uint4*)xt)[v] = cvt8(x + src);
  }

  // WcF[w8 0..191][colG 0..4095]: w8<64 -> Wx k=w8*8 ; w8>=64 -> Wh k=(w8-64)*8
  for (int o = gid; o < 192 * 4096; o += gsz) {
    int w8 = o >> 12;
    int colG = o & 4095;
    int unit = ((colG >> 6) << 4) + (((colG >> 5) & 1) << 3) + ((colG >> 2) & 7);
    int g = colG & 3;
    const float* Whp = (g == 0) ? Whf : (g == 1) ? Whi : (g == 2) ? Whg : Who;
    const float* Wxp = (g == 0) ? Wxf : (g == 1) ? Wxi : (g == 2) ? Wxg : Wxo;
    const float* s = (w8 < 64) ? (Wxp + (size_t)unit * 512 + w8 * 8)
                               : (Whp + (size_t)unit * 1024 + (w8 - 64) * 8);
    ((uint4*)Wc)[o] = cvt8(s);
  }

  // bias (colG-indexed)
  for (int n = gid; n < 4096; n += gsz) {
    int unit = ((n >> 6) << 4) + (((n >> 5) & 1) << 3) + ((n >> 2) & 7);
    int g = n & 3;
    const float* bp = (g == 0) ? bfp : (g == 1) ? bip : (g == 2) ? bgp : bop;
    bc[n] = bp[unit];
  }

  // Why -> bf16 (row-major [o][k])
  for (int v = gid; v < (O_ * H_ / 8); v += gsz) {
    int flat = v * 8;
    *(uint4*)(WhyT + flat) = cvt8(Why + flat);
  }

  // zero hA[0] and hA[1]
  for (int v = gid; v < 2 * 16384; v += gsz) {
    uint4 z; z.x = 0; z.y = 0; z.z = 0; z.w = 0;
    ((uint4*)hbuf)[v] = z;
  }
}

// ------------------------------------------------------ persistent LSTM ----
__global__ __launch_bounds__(256, 1) void lstm_seq(
    const u16* __restrict__ xt, const u16* __restrict__ Wc,
    const float* __restrict__ bc, u16* __restrict__ hbuf,
    const u16* __restrict__ WhyT, const float* __restrict__ WhyB,
    float* __restrict__ out, u32* __restrict__ barrier, int rotFlag)
{
  __shared__ float scr[2048];   // cross-kh partial-sum exchange (8 KB)
  __shared__ u16 hstage[512];   // h gather tile: [row 0..31][unitL 0..15]

  const int tid  = threadIdx.x;
  const int lane = tid & 63;
  const int w    = tid >> 6;
  const int ct   = w & 1;             // col tile (32 cols)
  const int kh   = w >> 1;            // K half
  // XCD-local clique decode: blockIdx%8 ~ XCD (MI355X heuristic). Clique rq
  // occupies XCD pair {2rq, 2rq+1}; cg parity = XCD within pair.
  const int rq   = (blockIdx.x & 7) >> 1;                      // rows rq*32..+31
  const int cg   = ((blockIdx.x >> 3) << 1) | (blockIdx.x & 1); // gate-cols cg*64..+63
  const bool rot = (rotFlag != 0);

  const int colN  = lane & 31;
  const int kgsel = lane >> 5;
  const int colG  = cg * 64 + ct * 32 + colN;
  const int gate  = colN & 3;                 // 0=f 1=i 2=g 3=o
  const int unitL = ct * 8 + (colN >> 2);
  const float bias = bc[colG];

  const uint4* xA4  = (const uint4*)xt;
  const uint4* WcF4 = (const uint4*)Wc;
  uint4*       HA4  = (uint4*)hbuf;

  const int xaOff = rq * 2048 + kh * 1024 + lane;                 // + t*8192 + kb*64
  const int xbOff = kh * 131072 + kgsel * 4096 + colG;            // + kb*8192
  const int haOff = rq * 4096 + kh * 2048 + lane;                 // + tb + kb*64
  const int hbOff = 262144 + kh * 262144 + kgsel * 4096 + colG;   // + kb*8192

  // per-K-half counters: producer -> barrier[rq*64 + (cg>>5)*32];
  // consumer wave kh -> barrier[rq*64 + kh*32]. 128B apart.
  const int prodFlag = rq * 64 + ((cg >> 5) << 5);
  const int consFlag = rq * 64 + (kh << 5);

  float c[8];
#pragma unroll
  for (int i = 0; i < 8; ++i) c[i] = 0.f;

  // One-time acquire: drop stale memset-poison / pre-prep lines so cached
  // reads of rotating h buffers (and the B preload) are correct.
  __builtin_amdgcn_fence(__ATOMIC_ACQUIRE, "agent");
  __syncthreads();

  // ---- park ALL weight B-frags in registers (192 regs/lane, AV->AGPR) ----
  v8s Bx[16], Bh[32];
  {
    const uint4* bx = WcF4 + xbOff;
#pragma unroll
    for (int kb = 0; kb < 16; ++kb)
      Bx[kb] = __builtin_bit_cast(v8s, bx[(size_t)kb * 8192]);
    const uint4* bh = WcF4 + hbOff;
#pragma unroll
    for (int kb = 0; kb < 32; ++kb)
      Bh[kb] = __builtin_bit_cast(v8s, bh[(size_t)kb * 8192]);
  }

  v16f acc0, acc1;

#pragma unroll 1
  for (int t = 0; t < S_; ++t) {
    const size_t tb = rot ? (size_t)t * 16384 : (size_t)(t & 1) * 16384;
    const size_t tn = rot ? (size_t)(t + 1) * 16384 : (size_t)((t & 1) ^ 1) * 16384;

#pragma unroll
    for (int i = 0; i < 16; ++i) { acc0[i] = 0.f; acc1[i] = 0.f; }

    // ---- x-phase: burst-load 16 A-frags, then MFMA against parked Bx ----
    {
      const uint4* ax = xA4 + (size_t)t * 8192 + xaOff;
      v8s xr[16];
#pragma unroll
      for (int kb = 0; kb < 16; ++kb)
        xr[kb] = __builtin_bit_cast(v8s, ax[kb * 64]);
#pragma unroll
      for (int kb = 0; kb < 16; ++kb) {
        if (kb & 1) acc1 = __builtin_amdgcn_mfma_f32_32x32x16_bf16(xr[kb], Bx[kb], acc1, 0, 0, 0);
        else        acc0 = __builtin_amdgcn_mfma_f32_32x32x16_bf16(xr[kb], Bx[kb], acc0, 0, 0, 0);
      }
    }

    // ---- wait: PER-WAVE lane0 poll of THIS K-HALF's counter (32 producers,
    // max-of-32 instead of max-of-64; halves decouple). No barrier. ----
    if (t > 0) {
      if (lane == 0) {
        u32 spins = 0;
        while (__hip_atomic_load(&barrier[consFlag], __ATOMIC_RELAXED,
                                 __HIP_MEMORY_SCOPE_AGENT) < 32u * (u32)t) {
          if (++spins > (1u << 22)) break;   // safety valve
        }
      }
      // implicit reconvergence gates the wave
    }

    // ---- h-phase: burst-load 32 A-frags, MFMA against parked Bh ----
    {
      const uint4* ah = HA4 + tb + haOff;
      v8s hr[32];
      if (rot) {
#pragma unroll
        for (int kb = 0; kb < 32; ++kb)
          hr[kb] = __builtin_bit_cast(v8s, ah[kb * 64]);
      } else {
#pragma unroll
        for (int kb = 0; kb < 32; ++kb)
          hr[kb] = __builtin_bit_cast(v8s, uc_ld16((const u16*)(ah + kb * 64)));
      }
#pragma unroll
      for (int kb = 0; kb < 32; ++kb) {
        if (kb & 1) acc1 = __builtin_amdgcn_mfma_f32_32x32x16_bf16(hr[kb], Bh[kb], acc1, 0, 0, 0);
        else        acc0 = __builtin_amdgcn_mfma_f32_32x32x16_bf16(hr[kb], Bh[kb], acc0, 0, 0, 0);
      }
    }

    // ---- cross-kh reduce, gates, state update ----
    float aT[16];
#pragma unroll
    for (int i = 0; i < 16; ++i) aT[i] = acc0[i] + acc1[i];
    {
      int h2 = 1 - kh;
#pragma unroll
      for (int i = 0; i < 8; ++i)
        scr[ct * 1024 + h2 * 512 + i * 64 + lane] = aT[h2 * 8 + i];
    }
    __syncthreads();

    const bool lastT = (t == S_ - 1);
#pragma unroll
    for (int i = 0; i < 8; ++i) {
      int r = kh * 8 + i;
      float pre = aT[r] + scr[ct * 1024 + kh * 512 + i * 64 + lane] + bias;
      // gate 2 -> tanh (overflow-safe), others -> sigmoid
      float e = __expf((gate == 2) ? (2.f * pre) : (-pre));
      float act = (gate == 2) ? (1.f - 2.f / (e + 1.f)) : (1.f / (1.f + e));
      int qb = lane & ~3;   // quad holds f,i,g,o of one (row,unit)
      float F = __shfl(act, qb + 0, 64);
      float I = __shfl(act, qb + 1, 64);
      float G = __shfl(act, qb + 2, 64);
      float O = __shfl(act, qb + 3, 64);
      float cn = fmaf(F, c[i], I * G);
      c[i] = cn;
      float e2 = __expf(2.f * cn);
      float hv = O * (1.f - 2.f / (e2 + 1.f));
      if (gate == 0) {
        int rowL = (r & 3) + ((r >> 2) << 3) + (kgsel << 2);   // 0..31
        hstage[rowL * 16 + unitL] = f2bf(hv);
        if (lastT) {
          int grow = rq * 32 + rowL;
          int gunit = cg * 16 + unitL;
          out[65536 + grow * H_ + gunit] = hv;    // h output (fp32)
          out[196608 + grow * H_ + gunit] = cn;   // c output (fp32)
        }
      }
    }
    __syncthreads();

    // ---- publish: wave0 only (other waves run ahead to x of t+1; any
    // wave's wait(t+1) exit implies our flag-add, which is after wave0's
    // hstage read -- hstage/scr reuse stays ordered). ----
    if (tid < 64) {
      int row = tid >> 1, u16sel = tid & 1;
      uint4 v = ((const uint4*)hstage)[tid];
      uc_st16((u16*)(HA4 + tn + rq * 4096 + (size_t)(2 * cg + u16sel) * 32 + row), v);
      asm volatile("s_waitcnt vmcnt(0)" ::: "memory");
      if (tid == 0)
        atomicAdd(&barrier[prodFlag], 1u);
    }
  }

  // ---- full barrier (8 half-counters), then out = h_final @ Why^T + b ----
  {
    if (tid < 8) {
      u32 spins = 0;
      while (__hip_atomic_load(&barrier[(tid >> 1) * 64 + (tid & 1) * 32],
                               __ATOMIC_RELAXED,
                               __HIP_MEMORY_SCOPE_AGENT) < 32u * (u32)S_) {
        __builtin_amdgcn_s_sleep(2);
        if (++spins > (1u << 22)) break;
      }
    }
  }
  __syncthreads();

  if (blockIdx.x < 32) {
    const int wg = blockIdx.x;
    const uint4* HF = HA4 + (rot ? (size_t)S_ * 16384 : 0);
    const int l15 = lane & 15;
    const int l4 = lane >> 4;
    const int colO = (wg << 4) + l15;
    v4f o0, o1;
#pragma unroll
    for (int i = 0; i < 4; ++i) { o0[i] = 0.f; o1[i] = 0.f; }
#pragma unroll 4
    for (int kc = 0; kc < 32; ++kc) {
      v8s bfrag = *(const v8s*)(WhyT + (size_t)colO * H_ + kc * 32 + (l4 << 3));
      size_t i0 = (size_t)w * 4096 + kc * 128 + l4 * 32 + l15;
      v8s a0, a1;
      if (rot) {
        a0 = __builtin_bit_cast(v8s, HF[i0]);
        a1 = __builtin_bit_cast(v8s, HF[i0 + 16]);
      } else {
        a0 = __builtin_bit_cast(v8s, uc_ld16((const u16*)(HF + i0)));
        a1 = __builtin_bit_cast(v8s, uc_ld16((const u16*)(HF + i0 + 16)));
      }
      o0 = __builtin_amdgcn_mfma_f32_16x16x32_bf16(a0, bfrag, o0, 0, 0, 0);
      o1 = __builtin_amdgcn_mfma_f32_16x16x32_bf16(a1, bfrag, o1, 0, 0, 0);
    }
    float bO = WhyB[colO];
#pragma unroll
    for (int r2 = 0; r2 < 4; ++r2) {
      int row = (w << 5) + (l4 << 2) + r2;
      out[row * O_ + colO] = o0[r2] + bO;
      out[(row + 16) * O_ + colO] = o1[r2] + bO;
    }
  }
}

// ------------------------------------------------------------- launch ----
extern "C" void kernel_launch(void* const* d_in, const int* in_sizes, int n_in,
                              void* d_out, int out_size, void* d_ws, size_t ws_size,
                              hipStream_t stream) {
  const float* x    = (const float*)d_in[0];
  const float* Wxf  = (const float*)d_in[1];
  const float* bf_  = (const float*)d_in[2];
  const float* Whf  = (const float*)d_in[3];
  const float* Wxi  = (const float*)d_in[4];
  const float* bi_  = (const float*)d_in[5];
  const float* Whi  = (const float*)d_in[6];
  const float* Wxg  = (const float*)d_in[7];
  const float* bg_  = (const float*)d_in[8];
  const float* Whg  = (const float*)d_in[9];
  const float* Wxo  = (const float*)d_in[10];
  const float* bo_  = (const float*)d_in[11];
  const float* Who  = (const float*)d_in[12];
  const float* Why  = (const float*)d_in[13];
  const float* Whyb = (const float*)d_in[14];

  char* ws = (char*)d_ws;
  u16*   xtp  = (u16*)(ws);                    // xA: 33,554,432 B
  u16*   Wcp  = (u16*)(ws + 33554432);         // WcF: 12,582,912 B
  float* bcp  = (float*)(ws + 46137344);       //     16,384 B
  u16*   WhyT = (u16*)(ws + 46153728);         //  1,048,576 B
  u32*   barp = (u32*)(ws + 47202304);         //      1,024 B (8 padded counters)
  u16*   hbuf = (u16*)(ws + 47203328);         // hA: rot 257*256KB else 512KB
  float* outp = (float*)d_out;

  const size_t need_rot = 47203328ull + 257ull * 262144ull;  // ~114.6 MB
  int rot = (ws_size >= need_rot) ? 1 : 0;

  lstm_prep<<<dim3(1024), dim3(256), 0, stream>>>(
      x, Whf, Whi, Whg, Who, Wxf, Wxi, Wxg, Wxo,
      bf_, bi_, bg_, bo_, Why, xtp, Wcp, bcp, WhyT, hbuf, barp);

  lstm_seq<<<dim3(256), dim3(256), 0, stream>>>(
      xtp, Wcp, bcp, hbuf, WhyT, Whyb, outp, barp, rot);
}